// Round 9
// baseline (203.534 us; speedup 1.0000x reference)
//
#include <hip/hip_runtime.h>

// B=4, C=C2=1024, E=1024, D=1024, NH(head dim)=16, G=64 groups. Rows B*C=4096.

typedef _Float16 f16x8 __attribute__((ext_vector_type(8)));
typedef _Float16 f16x4 __attribute__((ext_vector_type(4)));
typedef _Float16 f16x2 __attribute__((ext_vector_type(2)));
typedef float    f32x4 __attribute__((ext_vector_type(4)));
typedef float    f32x16 __attribute__((ext_vector_type(16)));

// global -> LDS direct DMA, 16 B per lane. LDS dest = wave-uniform base + lane*16.
#define GLOAD_LDS16(gp, lp)                                              \
    __builtin_amdgcn_global_load_lds(                                    \
        (const __attribute__((address_space(1))) void*)(gp),             \
        (__attribute__((address_space(3))) void*)(lp), 16, 0, 0)

static __device__ __forceinline__ f16x8 pack8f(const float* p) {
    f16x2 a = __builtin_bit_cast(f16x2, __builtin_amdgcn_cvt_pkrtz(p[0], p[1]));
    f16x2 b = __builtin_bit_cast(f16x2, __builtin_amdgcn_cvt_pkrtz(p[2], p[3]));
    f16x2 c = __builtin_bit_cast(f16x2, __builtin_amdgcn_cvt_pkrtz(p[4], p[5]));
    f16x2 d = __builtin_bit_cast(f16x2, __builtin_amdgcn_cvt_pkrtz(p[6], p[7]));
    f16x8 r;
    r[0] = a[0]; r[1] = a[1]; r[2] = b[0]; r[3] = b[1];
    r[4] = c[0]; r[5] = c[1]; r[6] = d[0]; r[7] = d[1];
    return r;
}

// ---- prep: fp32->fp16 convert of x1,x2 (blocks 0..8191) + transpose-convert of the
// ---- 4 weights into (N,K) f16 (blocks 8192..12287), one launch ----
__global__ __launch_bounds__(256) void prep_kernel(
        const float* __restrict__ x1, const float* __restrict__ x2,
        const float* __restrict__ W0, const float* __restrict__ W1,
        const float* __restrict__ W2, const float* __restrict__ W3,
        _Float16* __restrict__ y1, _Float16* __restrict__ y2,
        _Float16* __restrict__ T0, _Float16* __restrict__ T1,
        _Float16* __restrict__ T2, _Float16* __restrict__ T3) {
    int bx = blockIdx.x, tid = threadIdx.x;
    if (bx < 8192) {
        int i = bx * 256 + tid;              // 2M float4 total
        const float* x = (i < 1048576) ? x1 : x2;
        _Float16* y = (i < 1048576) ? y1 : y2;
        int j = i & 1048575;
        float4 v = ((const float4*)x)[j];
        f16x4 h = { (_Float16)v.x, (_Float16)v.y, (_Float16)v.z, (_Float16)v.w };
        ((f16x4*)y)[j] = h;
    } else {
        int z = (bx - 8192) >> 10;
        const float* W = (z == 0) ? W0 : (z == 1) ? W1 : (z == 2) ? W2 : W3;
        _Float16* WT = (z == 0) ? T0 : (z == 1) ? T1 : (z == 2) ? T2 : T3;
        int t = (bx - 8192) & 1023;
        int c0 = (t & 31) * 32, r0 = (t >> 5) * 32;
        __shared__ float tile[32][33];
        int tx = tid & 31, ty = tid >> 5;    // 32 x 8
#pragma unroll
        for (int i = 0; i < 32; i += 8)
            tile[ty + i][tx] = W[(r0 + ty + i) * 1024 + (c0 + tx)];
        __syncthreads();
#pragma unroll
        for (int i = 0; i < 32; i += 8)
            WT[(c0 + ty + i) * 1024 + (r0 + tx)] = (_Float16)tile[tx][ty + i];
    }
}

// ------------- m97-style 128x128 GEMM body (pre-offset pointers, K=1024) -------------
// A_tile: A + m0*1024; BT_tile: BT + n0*1024 (rows n0..n0+127 of (N,K) matrix);
// C_tile: C + m0*1024 + n0c. block 256 (4 waves, 2x2), BK=64, global_load_lds w16.
template <bool OUTF32>
static __device__ __forceinline__ void gemm_body(const _Float16* __restrict__ Atile,
                                                 const _Float16* __restrict__ BTtile,
                                                 void* __restrict__ Ctile,
                                                 _Float16* As, _Float16* Bs) {
    const int tid = threadIdx.x, lane = tid & 63, wave = tid >> 6;
    const int wm = wave >> 1, wn = wave & 1;
    const int col = lane & 15, quad = lane >> 4;

    f32x4 acc[4][4];
#pragma unroll
    for (int i = 0; i < 4; i++)
#pragma unroll
        for (int j = 0; j < 4; j++) acc[i][j] = (f32x4){0.f, 0.f, 0.f, 0.f};

    const int srow = wave * 8 + (lane >> 3);
    const int sch = (lane & 7) * 8;
    const _Float16* Ag = Atile + (size_t)srow * 1024 + sch;
    const _Float16* Bg = BTtile + (size_t)srow * 1024 + sch;
    _Float16* Asl = As + wave * 512;
    _Float16* Bsl = Bs + wave * 512;

    for (int kt = 0; kt < 16; kt++) {
        __syncthreads();
#pragma unroll
        for (int c = 0; c < 4; c++) {
            GLOAD_LDS16(Ag + (size_t)(c * 32) * 1024 + kt * 64, Asl + c * 2048);
            GLOAD_LDS16(Bg + (size_t)(c * 32) * 1024 + kt * 64, Bsl + c * 2048);
        }
        __syncthreads();
#pragma unroll
        for (int ki = 0; ki < 2; ki++) {
            f16x8 af[4], bf[4];
#pragma unroll
            for (int i = 0; i < 4; i++)
                af[i] = *(const f16x8*)(As + (wm * 64 + i * 16 + col) * 64 + ki * 32 + quad * 8);
#pragma unroll
            for (int j = 0; j < 4; j++)
                bf[j] = *(const f16x8*)(Bs + (wn * 64 + j * 16 + col) * 64 + ki * 32 + quad * 8);
#pragma unroll
            for (int i = 0; i < 4; i++)
#pragma unroll
                for (int j = 0; j < 4; j++)
                    acc[i][j] = __builtin_amdgcn_mfma_f32_16x16x32_f16(af[i], bf[j], acc[i][j], 0, 0, 0);
        }
    }

#pragma unroll
    for (int i = 0; i < 4; i++)
#pragma unroll
        for (int ii = 0; ii < 4; ii++) {
            int row = wm * 64 + i * 16 + quad * 4 + ii;
#pragma unroll
            for (int j = 0; j < 4; j++) {
                int cc = wn * 64 + j * 16 + col;
                if (OUTF32) ((float*)Ctile)[(size_t)row * 1024 + cc] = acc[i][j][ii];
                else ((_Float16*)Ctile)[(size_t)row * 1024 + cc] = (_Float16)acc[i][j][ii];
            }
        }
}

// Fused Q + (KV as N=2048) projections, flat 768-block grid:
//  gx < 256 : Q  = x1h @ WqT^T   (m = gx>>3, n-block = gx&7)
//  gx >= 256: KV = x2h @ [WkT;WvT]^T (idx = gx-256: m = idx>>4, n-block16 = idx&15;
//             WkT/WvT are contiguous in ws so rows 0..2047 of the stacked BT work directly)
__global__ __launch_bounds__(256, 3) void gemm_qkv_kernel(
        const _Float16* __restrict__ x1h, const _Float16* __restrict__ x2h,
        const _Float16* __restrict__ WqT, const _Float16* __restrict__ WkvT,
        _Float16* __restrict__ Qh, _Float16* __restrict__ Kh, _Float16* __restrict__ Vh) {
    __shared__ _Float16 As[128 * 64], Bs[128 * 64];
    int gx = blockIdx.x;
    const _Float16 *A, *BT;
    _Float16* C;
    int m0, n0;
    if (gx < 256) {
        m0 = (gx >> 3) * 128; n0 = (gx & 7) * 128;
        A = x1h; BT = WqT + (size_t)n0 * 1024; C = Qh + n0;
    } else {
        int idx = gx - 256;
        m0 = (idx >> 4) * 128;
        int nb = idx & 15;
        n0 = nb * 128;                        // 0..2047 within stacked KV
        A = x2h; BT = WkvT + (size_t)n0 * 1024;
        C = (nb < 8) ? (Kh + n0) : (Vh + (n0 - 1024));
    }
    gemm_body<false>(A + (size_t)m0 * 1024, BT, (void*)(C + (size_t)m0 * 1024), As, Bs);
}

__global__ __launch_bounds__(256, 3) void gemm_wo_kernel(const _Float16* __restrict__ Ah,
                                                         const _Float16* __restrict__ WoT,
                                                         float* __restrict__ out) {
    __shared__ _Float16 As[128 * 64], Bs[128 * 64];
    int m0 = blockIdx.y * 128, n0 = blockIdx.x * 128;
    gemm_body<true>(Ah + (size_t)m0 * 1024, WoT + (size_t)n0 * 1024,
                    (void*)(out + (size_t)m0 * 1024 + n0), As, Bs);
}

// ------------- MFMA flash attention (fixed-max softmax), per (b,g) pair -------------
// grid (8 q-chunks, 256 pairs) = 2048 blocks, block 256 (4 waves), 16.4 KB LDS
// (256-key K/V chunks) -> 8 blocks/CU = 32 waves/CU (thread-capped, 100%).
// Wave: 32 queries x 1024 keys, 32 keys/iter (R7 math):
//   S32 = Khat.Q^T via ONE mfma_32x32x16; Khat row m = physical key perm(m)
//   (swap bits 2<->3), so C-layout regs 0-7 / 8-15, exp'd + packed, ARE the B-frags
//   of two mfma_32x32x16 PV calls. PV A rows 0-15 = V^T, rows 16-31 = broadcast
//   ones -> L fused into acc regs 8-15.
__global__ __launch_bounds__(256, 8) void attn_kernel(const _Float16* __restrict__ Qh,
                                                      const _Float16* __restrict__ Kh,
                                                      const _Float16* __restrict__ Vh,
                                                      _Float16* __restrict__ Ah) {
    int pair = blockIdx.y;
    int b = pair >> 6, g = pair & 63;
    __shared__ _Float16 KA[4096];    // [t:8][lane:64][8 halves] pre-permuted A-frags, 8 KB
    __shared__ _Float16 VA[4096];    // [pvblk:16][slot:32][8 halves], slot=head+16*h5, 8 KB
    __shared__ _Float16 ones[8];

    const _Float16* Kg = Kh + (size_t)(b * 1024) * 1024 + g * 16;
    const _Float16* Vg = Vh + (size_t)(b * 1024) * 1024 + g * 16;
    int tid = threadIdx.x;
    if (tid < 8) ones[tid] = (_Float16)1.f;

    int lane = tid & 63, wave = tid >> 6;    // wave 0..3
    int n = lane & 31, h5 = lane >> 5;       // n = q (S/PV col), also PV A-row m
    int q0 = blockIdx.x * 128 + wave * 32;

    // Q B-frag: B[k=head=h5*8+j][n=q]; fold 0.25*log2(e) -> scores in log2 domain.
    f16x8 qf;
    {
        f16x8 t = *(const f16x8*)(Qh + (size_t)(b * 1024 + q0 + n) * 1024 + g * 16 + h5 * 8);
#pragma unroll
        for (int j = 0; j < 8; j++) qf[j] = (_Float16)((float)t[j] * 0.360673760f);
    }

    f32x16 acc = {0.f, 0.f, 0.f, 0.f, 0.f, 0.f, 0.f, 0.f,
                  0.f, 0.f, 0.f, 0.f, 0.f, 0.f, 0.f, 0.f};
    const f32x16 zero16 = acc;
    // V A-frag source: real V rows for m<16, broadcast ones for m>=16.
    const _Float16* vbase = (n < 16) ? (VA + (n + 16 * h5) * 8) : ones;
    const int vstep = (n < 16) ? 256 : 0;    // advance per pvblk only for real rows

    for (int c = 0; c < 4; c++) {            // 256-key chunks
        if (c) __syncthreads();
#pragma unroll
        for (int it = 0; it < 2; it++) {     // K: permuted staging, uint4 per task
            int row = it * 128 + (tid >> 1); // key within chunk 0..255
            int part = tid & 1;
            int pm = (row & 19) | ((row & 4) << 1) | ((row & 8) >> 1);  // swap bits 2,3 of low5
            *(uint4*)(KA + (((row >> 5) * 64) + pm + 32 * part) * 8) =
                *(const uint4*)(Kg + (size_t)(c * 256 + row) * 1024 + part * 8);
        }
#pragma unroll
        for (int it = 0; it < 2; it++) {     // V: transpose into [pvblk][slot][j_k]
            int row = it * 128 + (tid >> 1); // key within chunk
            int part = tid & 1;
            f16x8 v = *(const f16x8*)(Vg + (size_t)(c * 256 + row) * 1024 + part * 8);
            // dst halves = pvblk*256 + (head + 16*hsel)*8 + j_k ; head = part*8+j
            int base = (row >> 4) * 256 + ((row >> 3) & 1) * 128 + part * 64 + (row & 7);
#pragma unroll
            for (int j = 0; j < 8; j++) VA[base + j * 8] = v[j];
        }
        __syncthreads();

#pragma unroll 2
        for (int t = 0; t < 8; t++) {        // 32 keys per iteration
            f16x8 ak = *(const f16x8*)(KA + (t * 64 + lane) * 8);
            f32x16 s = __builtin_amdgcn_mfma_f32_32x32x16_f16(ak, qf, zero16, 0, 0, 0);
            float p[16];
#pragma unroll
            for (int i = 0; i < 16; i++) p[i] = __builtin_amdgcn_exp2f(s[i]);
            f16x8 pb0 = pack8f(p);           // keys t*32 + 0..15  (k=h5*8+j)
            f16x8 pb1 = pack8f(p + 8);       // keys t*32 + 16..31
            f16x8 av0 = *(const f16x8*)(vbase + (2 * t) * vstep);
            f16x8 av1 = *(const f16x8*)(vbase + (2 * t + 1) * vstep);
            acc = __builtin_amdgcn_mfma_f32_32x32x16_f16(av0, pb0, acc, 0, 0, 0);
            acc = __builtin_amdgcn_mfma_f32_32x32x16_f16(av1, pb1, acc, 0, 0, 0);
        }
    }

    // acc C-layout: col q=n; regs 0-7 -> heads, regs 8-15 -> L (all equal = key-sum).
    float rl = 1.0f / acc[8];
    f16x4 o0, o1;
#pragma unroll
    for (int i = 0; i < 4; i++) o0[i] = (_Float16)(acc[i] * rl);       // heads 4*h5+0..3
#pragma unroll
    for (int i = 0; i < 4; i++) o1[i] = (_Float16)(acc[4 + i] * rl);   // heads 4*h5+8..11
    _Float16* ob = Ah + (size_t)(b * 1024 + q0 + n) * 1024 + g * 16 + h5 * 4;
    *(f16x4*)(ob) = o0;
    *(f16x4*)(ob + 8) = o1;
}

extern "C" void kernel_launch(void* const* d_in, const int* in_sizes, int n_in,
                              void* d_out, int out_size, void* d_ws, size_t ws_size,
                              hipStream_t stream) {
    const float* x1 = (const float*)d_in[0];
    const float* x2 = (const float*)d_in[1];
    const float* Wq = (const float*)d_in[2];
    const float* Wk = (const float*)d_in[3];
    const float* Wv = (const float*)d_in[4];
    const float* Wo = (const float*)d_in[5];

    char* ws = (char*)d_ws;
    const size_t MB = 1u << 20;
    if (ws_size < 56 * MB) return;

    _Float16* x1h = (_Float16*)(ws + 0 * MB);   // 4096x1024
    _Float16* x2h = (_Float16*)(ws + 8 * MB);   // 4096x1024
    _Float16* WqT = (_Float16*)(ws + 16 * MB);  // 1024x1024 (N,K)
    _Float16* WkT = (_Float16*)(ws + 18 * MB);  // contiguous with WvT -> stacked (2048,1024)
    _Float16* WvT = (_Float16*)(ws + 20 * MB);
    _Float16* WoT = (_Float16*)(ws + 22 * MB);
    _Float16* Qh  = (_Float16*)(ws + 24 * MB);  // 4096x1024
    _Float16* Kh  = (_Float16*)(ws + 32 * MB);
    _Float16* Vh  = (_Float16*)(ws + 40 * MB);
    _Float16* Ah  = (_Float16*)(ws + 48 * MB);

    prep_kernel<<<12288, 256, 0, stream>>>(x1, x2, Wq, Wk, Wv, Wo,
                                           x1h, x2h, WqT, WkT, WvT, WoT);

    gemm_qkv_kernel<<<768, 256, 0, stream>>>(x1h, x2h, WqT, WkT, Qh, Kh, Vh);

    attn_kernel<<<dim3(8, 256), 256, 0, stream>>>(Qh, Kh, Vh, Ah);

    gemm_wo_kernel<<<dim3(8, 32), 256, 0, stream>>>(Ah, WoT, (float*)d_out);
}

// Round 10
// 197.435 us; speedup vs baseline: 1.0309x; 1.0309x over previous
//
#include <hip/hip_runtime.h>

// B=4, C=C2=1024, E=1024, D=1024, NH(head dim)=16, G=64 groups. Rows B*C=4096.

typedef _Float16 f16x8 __attribute__((ext_vector_type(8)));
typedef _Float16 f16x4 __attribute__((ext_vector_type(4)));
typedef _Float16 f16x2 __attribute__((ext_vector_type(2)));
typedef float    f32x4 __attribute__((ext_vector_type(4)));
typedef float    f32x16 __attribute__((ext_vector_type(16)));

// global -> LDS direct DMA, 16 B per lane. LDS dest = wave-uniform base + lane*16.
#define GLOAD_LDS16(gp, lp)                                              \
    __builtin_amdgcn_global_load_lds(                                    \
        (const __attribute__((address_space(1))) void*)(gp),             \
        (__attribute__((address_space(3))) void*)(lp), 16, 0, 0)

static __device__ __forceinline__ f16x8 pack8f(const float* p) {
    f16x2 a = __builtin_bit_cast(f16x2, __builtin_amdgcn_cvt_pkrtz(p[0], p[1]));
    f16x2 b = __builtin_bit_cast(f16x2, __builtin_amdgcn_cvt_pkrtz(p[2], p[3]));
    f16x2 c = __builtin_bit_cast(f16x2, __builtin_amdgcn_cvt_pkrtz(p[4], p[5]));
    f16x2 d = __builtin_bit_cast(f16x2, __builtin_amdgcn_cvt_pkrtz(p[6], p[7]));
    f16x8 r;
    r[0] = a[0]; r[1] = a[1]; r[2] = b[0]; r[3] = b[1];
    r[4] = c[0]; r[5] = c[1]; r[6] = d[0]; r[7] = d[1];
    return r;
}

// ---- prep: fp32->fp16 convert of x1,x2 (blocks 0..8191) + transpose-convert of the
// ---- 4 weights into (N,K) f16 (blocks 8192..12287), one launch ----
__global__ __launch_bounds__(256) void prep_kernel(
        const float* __restrict__ x1, const float* __restrict__ x2,
        const float* __restrict__ W0, const float* __restrict__ W1,
        const float* __restrict__ W2, const float* __restrict__ W3,
        _Float16* __restrict__ y1, _Float16* __restrict__ y2,
        _Float16* __restrict__ T0, _Float16* __restrict__ T1,
        _Float16* __restrict__ T2, _Float16* __restrict__ T3) {
    int bx = blockIdx.x, tid = threadIdx.x;
    if (bx < 8192) {
        int i = bx * 256 + tid;              // 2M float4 total
        const float* x = (i < 1048576) ? x1 : x2;
        _Float16* y = (i < 1048576) ? y1 : y2;
        int j = i & 1048575;
        float4 v = ((const float4*)x)[j];
        f16x4 h = { (_Float16)v.x, (_Float16)v.y, (_Float16)v.z, (_Float16)v.w };
        ((f16x4*)y)[j] = h;
    } else {
        int z = (bx - 8192) >> 10;
        const float* W = (z == 0) ? W0 : (z == 1) ? W1 : (z == 2) ? W2 : W3;
        _Float16* WT = (z == 0) ? T0 : (z == 1) ? T1 : (z == 2) ? T2 : T3;
        int t = (bx - 8192) & 1023;
        int c0 = (t & 31) * 32, r0 = (t >> 5) * 32;
        __shared__ float tile[32][33];
        int tx = tid & 31, ty = tid >> 5;    // 32 x 8
#pragma unroll
        for (int i = 0; i < 32; i += 8)
            tile[ty + i][tx] = W[(r0 + ty + i) * 1024 + (c0 + tx)];
        __syncthreads();
#pragma unroll
        for (int i = 0; i < 32; i += 8)
            WT[(c0 + ty + i) * 1024 + (r0 + tx)] = (_Float16)tile[tx][ty + i];
    }
}

// ------------- m97-style MTx128 GEMM body (pre-offset pointers, K=1024) -------------
// block 256 (4 waves, 2x2 over MT x 128), BK=64, global_load_lds w16, 16x16x32 MFMA.
// MT=128: 4x4 accs/wave; MT=64: 2x4 accs/wave (for small grids -> more blocks/CU).
template <int MT, bool OUTF32>
static __device__ __forceinline__ void gemm_body(const _Float16* __restrict__ Atile,
                                                 const _Float16* __restrict__ BTtile,
                                                 void* __restrict__ Ctile,
                                                 _Float16* As, _Float16* Bs) {
    constexpr int AF = MT / 32;              // A staging rounds & m-frags per wave
    const int tid = threadIdx.x, lane = tid & 63, wave = tid >> 6;
    const int wm = wave >> 1, wn = wave & 1;
    const int col = lane & 15, quad = lane >> 4;

    f32x4 acc[AF][4];
#pragma unroll
    for (int i = 0; i < AF; i++)
#pragma unroll
        for (int j = 0; j < 4; j++) acc[i][j] = (f32x4){0.f, 0.f, 0.f, 0.f};

    const int srow = wave * 8 + (lane >> 3);
    const int sch = (lane & 7) * 8;
    const _Float16* Ag = Atile + (size_t)srow * 1024 + sch;
    const _Float16* Bg = BTtile + (size_t)srow * 1024 + sch;
    _Float16* Asl = As + wave * 512;
    _Float16* Bsl = Bs + wave * 512;

    for (int kt = 0; kt < 16; kt++) {
        __syncthreads();
#pragma unroll
        for (int c = 0; c < AF; c++)
            GLOAD_LDS16(Ag + (size_t)(c * 32) * 1024 + kt * 64, Asl + c * 2048);
#pragma unroll
        for (int c = 0; c < 4; c++)
            GLOAD_LDS16(Bg + (size_t)(c * 32) * 1024 + kt * 64, Bsl + c * 2048);
        __syncthreads();
#pragma unroll
        for (int ki = 0; ki < 2; ki++) {
            f16x8 af[AF], bf[4];
#pragma unroll
            for (int i = 0; i < AF; i++)
                af[i] = *(const f16x8*)(As + (wm * (MT / 2) + i * 16 + col) * 64 + ki * 32 + quad * 8);
#pragma unroll
            for (int j = 0; j < 4; j++)
                bf[j] = *(const f16x8*)(Bs + (wn * 64 + j * 16 + col) * 64 + ki * 32 + quad * 8);
#pragma unroll
            for (int i = 0; i < AF; i++)
#pragma unroll
                for (int j = 0; j < 4; j++)
                    acc[i][j] = __builtin_amdgcn_mfma_f32_16x16x32_f16(af[i], bf[j], acc[i][j], 0, 0, 0);
        }
    }

#pragma unroll
    for (int i = 0; i < AF; i++)
#pragma unroll
        for (int ii = 0; ii < 4; ii++) {
            int row = wm * (MT / 2) + i * 16 + quad * 4 + ii;
#pragma unroll
            for (int j = 0; j < 4; j++) {
                int cc = wn * 64 + j * 16 + col;
                if (OUTF32) ((float*)Ctile)[(size_t)row * 1024 + cc] = acc[i][j][ii];
                else ((_Float16*)Ctile)[(size_t)row * 1024 + cc] = (_Float16)acc[i][j][ii];
            }
        }
}

// Fused Q + (KV as N=2048) projections, flat 768-block grid (128x128 tiles):
__global__ __launch_bounds__(256, 3) void gemm_qkv_kernel(
        const _Float16* __restrict__ x1h, const _Float16* __restrict__ x2h,
        const _Float16* __restrict__ WqT, const _Float16* __restrict__ WkvT,
        _Float16* __restrict__ Qh, _Float16* __restrict__ Kh, _Float16* __restrict__ Vh) {
    __shared__ _Float16 As[128 * 64], Bs[128 * 64];
    int gx = blockIdx.x;
    const _Float16 *A, *BT;
    _Float16* C;
    int m0, n0;
    if (gx < 256) {
        m0 = (gx >> 3) * 128; n0 = (gx & 7) * 128;
        A = x1h; BT = WqT + (size_t)n0 * 1024; C = Qh + n0;
    } else {
        int idx = gx - 256;
        m0 = (idx >> 4) * 128;
        int nb = idx & 15;
        n0 = nb * 128;                        // 0..2047 within stacked KV
        A = x2h; BT = WkvT + (size_t)n0 * 1024;
        C = (nb < 8) ? (Kh + n0) : (Vh + (n0 - 1024));
    }
    gemm_body<128, false>(A + (size_t)m0 * 1024, BT, (void*)(C + (size_t)m0 * 1024), As, Bs);
}

// Wo GEMM: 64x128 tiles -> 512 blocks (2 blocks/CU co-residency vs 1 at 128x128).
__global__ __launch_bounds__(256, 4) void gemm_wo_kernel(const _Float16* __restrict__ Ah,
                                                         const _Float16* __restrict__ WoT,
                                                         float* __restrict__ out) {
    __shared__ _Float16 As[64 * 64], Bs[128 * 64];
    int gx = blockIdx.x;
    int m0 = (gx >> 3) * 64, n0 = (gx & 7) * 128;
    gemm_body<64, true>(Ah + (size_t)m0 * 1024, WoT + (size_t)n0 * 1024,
                        (void*)(out + (size_t)m0 * 1024 + n0), As, Bs);
}

// ------------- MFMA flash attention (fixed-max softmax), per (b,g) pair -------------
// grid (4 q-chunks, 256 pairs) = 1024 blocks, block 256 (4 waves), 32.8 KB LDS
// (512-key K/V chunks) -> 4 blocks/CU, 16 waves/CU. Wave: 64 queries as TWO
// independent 32-q chains sharing each ak/av read (R8-verified 1.46x issue density),
// at R9's measured residency (R8's regression was block-residency loss, fixed here).
//   S32 = Khat.Q^T via ONE mfma_32x32x16; Khat row m = physical key perm(m)
//   (swap bits 2<->3), so C-layout regs 0-7 / 8-15, exp'd + packed, ARE the B-frags
//   of two mfma_32x32x16 PV calls. PV A rows 0-15 = V^T, rows 16-31 = broadcast
//   ones -> L fused into acc regs 8-15.
__global__ __launch_bounds__(256, 8) void attn_kernel(const _Float16* __restrict__ Qh,
                                                      const _Float16* __restrict__ Kh,
                                                      const _Float16* __restrict__ Vh,
                                                      _Float16* __restrict__ Ah) {
    int pair = blockIdx.y;
    int b = pair >> 6, g = pair & 63;
    __shared__ _Float16 KA[8192];    // [t:16][lane:64][8 halves] pre-permuted A-frags, 16 KB
    __shared__ _Float16 VA[8192];    // [pvblk:32][slot:32][8 halves], slot=head+16*h5, 16 KB
    __shared__ _Float16 ones[8];

    const _Float16* Kg = Kh + (size_t)(b * 1024) * 1024 + g * 16;
    const _Float16* Vg = Vh + (size_t)(b * 1024) * 1024 + g * 16;
    int tid = threadIdx.x;
    if (tid < 8) ones[tid] = (_Float16)1.f;

    int lane = tid & 63, wave = tid >> 6;    // wave 0..3
    int n = lane & 31, h5 = lane >> 5;       // n = q (S/PV col), also PV A-row m
    int q0 = blockIdx.x * 256 + wave * 64;   // two q-groups: q0+0..31, q0+32..63

    // 2 Q B-frags: B[k=head=h5*8+j][n=q]; fold 0.25*log2(e) -> scores in log2 domain.
    f16x8 qf[2];
#pragma unroll
    for (int qg = 0; qg < 2; qg++) {
        f16x8 t = *(const f16x8*)(Qh + (size_t)(b * 1024 + q0 + qg * 32 + n) * 1024 +
                                  g * 16 + h5 * 8);
#pragma unroll
        for (int j = 0; j < 8; j++) qf[qg][j] = (_Float16)((float)t[j] * 0.360673760f);
    }

    f32x16 acc[2];
#pragma unroll
    for (int qg = 0; qg < 2; qg++)
        acc[qg] = (f32x16){0.f, 0.f, 0.f, 0.f, 0.f, 0.f, 0.f, 0.f,
                           0.f, 0.f, 0.f, 0.f, 0.f, 0.f, 0.f, 0.f};
    const f32x16 zero16 = acc[0];
    // V A-frag source: real V rows for m<16, broadcast ones for m>=16.
    const _Float16* vbase = (n < 16) ? (VA + (n + 16 * h5) * 8) : ones;
    const int vstep = (n < 16) ? 256 : 0;    // advance per pvblk only for real rows

    for (int c = 0; c < 2; c++) {            // 512-key chunks
        if (c) __syncthreads();
#pragma unroll
        for (int it = 0; it < 4; it++) {     // K: permuted staging, uint4 per task
            int row = it * 128 + (tid >> 1); // key within chunk 0..511
            int part = tid & 1;
            int pm = (row & 19) | ((row & 4) << 1) | ((row & 8) >> 1);  // swap bits 2,3 of low5
            *(uint4*)(KA + (((row >> 5) * 64) + pm + 32 * part) * 8) =
                *(const uint4*)(Kg + (size_t)(c * 512 + row) * 1024 + part * 8);
        }
#pragma unroll
        for (int it = 0; it < 4; it++) {     // V: transpose into [pvblk][slot][j_k]
            int row = it * 128 + (tid >> 1); // key within chunk
            int part = tid & 1;
            f16x8 v = *(const f16x8*)(Vg + (size_t)(c * 512 + row) * 1024 + part * 8);
            // dst halves = pvblk*256 + (head + 16*hsel)*8 + j_k ; head = part*8+j
            int base = (row >> 4) * 256 + ((row >> 3) & 1) * 128 + part * 64 + (row & 7);
#pragma unroll
            for (int j = 0; j < 8; j++) VA[base + j * 8] = v[j];
        }
        __syncthreads();

#pragma unroll 2
        for (int t = 0; t < 16; t++) {       // 32 keys per iteration, 2 q-chains
            f16x8 ak = *(const f16x8*)(KA + (t * 64 + lane) * 8);
            f16x8 av0 = *(const f16x8*)(vbase + (2 * t) * vstep);
            f16x8 av1 = *(const f16x8*)(vbase + (2 * t + 1) * vstep);
#pragma unroll
            for (int qg = 0; qg < 2; qg++) {
                f32x16 s = __builtin_amdgcn_mfma_f32_32x32x16_f16(ak, qf[qg], zero16, 0, 0, 0);
                float p[16];
#pragma unroll
                for (int i = 0; i < 16; i++) p[i] = __builtin_amdgcn_exp2f(s[i]);
                f16x8 pb0 = pack8f(p);       // keys t*32 + 0..15  (k=h5*8+j)
                f16x8 pb1 = pack8f(p + 8);   // keys t*32 + 16..31
                acc[qg] = __builtin_amdgcn_mfma_f32_32x32x16_f16(av0, pb0, acc[qg], 0, 0, 0);
                acc[qg] = __builtin_amdgcn_mfma_f32_32x32x16_f16(av1, pb1, acc[qg], 0, 0, 0);
            }
        }
    }

    // acc C-layout: col q=n; regs 0-7 -> heads, regs 8-15 -> L (all equal = key-sum).
#pragma unroll
    for (int qg = 0; qg < 2; qg++) {
        float rl = 1.0f / acc[qg][8];
        f16x4 o0, o1;
#pragma unroll
        for (int i = 0; i < 4; i++) o0[i] = (_Float16)(acc[qg][i] * rl);     // heads 4*h5+0..3
#pragma unroll
        for (int i = 0; i < 4; i++) o1[i] = (_Float16)(acc[qg][4 + i] * rl); // heads 4*h5+8..11
        _Float16* ob = Ah + (size_t)(b * 1024 + q0 + qg * 32 + n) * 1024 + g * 16 + h5 * 4;
        *(f16x4*)(ob) = o0;
        *(f16x4*)(ob + 8) = o1;
    }
}

extern "C" void kernel_launch(void* const* d_in, const int* in_sizes, int n_in,
                              void* d_out, int out_size, void* d_ws, size_t ws_size,
                              hipStream_t stream) {
    const float* x1 = (const float*)d_in[0];
    const float* x2 = (const float*)d_in[1];
    const float* Wq = (const float*)d_in[2];
    const float* Wk = (const float*)d_in[3];
    const float* Wv = (const float*)d_in[4];
    const float* Wo = (const float*)d_in[5];

    char* ws = (char*)d_ws;
    const size_t MB = 1u << 20;
    if (ws_size < 56 * MB) return;

    _Float16* x1h = (_Float16*)(ws + 0 * MB);   // 4096x1024
    _Float16* x2h = (_Float16*)(ws + 8 * MB);   // 4096x1024
    _Float16* WqT = (_Float16*)(ws + 16 * MB);  // 1024x1024 (N,K)
    _Float16* WkT = (_Float16*)(ws + 18 * MB);  // contiguous with WvT -> stacked (2048,1024)
    _Float16* WvT = (_Float16*)(ws + 20 * MB);
    _Float16* WoT = (_Float16*)(ws + 22 * MB);
    _Float16* Qh  = (_Float16*)(ws + 24 * MB);  // 4096x1024
    _Float16* Kh  = (_Float16*)(ws + 32 * MB);
    _Float16* Vh  = (_Float16*)(ws + 40 * MB);
    _Float16* Ah  = (_Float16*)(ws + 48 * MB);

    prep_kernel<<<12288, 256, 0, stream>>>(x1, x2, Wq, Wk, Wv, Wo,
                                           x1h, x2h, WqT, WkT, WvT, WoT);

    gemm_qkv_kernel<<<768, 256, 0, stream>>>(x1h, x2h, WqT, WkT, Qh, Kh, Vh);

    attn_kernel<<<dim3(4, 256), 256, 0, stream>>>(Qh, Kh, Vh, Ah);

    gemm_wo_kernel<<<512, 256, 0, stream>>>(Ah, WoT, (float*)d_out);
}

// Round 11
// 194.811 us; speedup vs baseline: 1.0448x; 1.0135x over previous
//
#include <hip/hip_runtime.h>

// B=4, C=C2=1024, E=1024, D=1024, NH(head dim)=16, G=64 groups. Rows B*C=4096.

typedef _Float16 f16x8 __attribute__((ext_vector_type(8)));
typedef _Float16 f16x4 __attribute__((ext_vector_type(4)));
typedef _Float16 f16x2 __attribute__((ext_vector_type(2)));
typedef float    f32x4 __attribute__((ext_vector_type(4)));
typedef float    f32x16 __attribute__((ext_vector_type(16)));

// global -> LDS direct DMA, 16 B per lane. LDS dest = wave-uniform base + lane*16.
#define GLOAD_LDS16(gp, lp)                                              \
    __builtin_amdgcn_global_load_lds(                                    \
        (const __attribute__((address_space(1))) void*)(gp),             \
        (__attribute__((address_space(3))) void*)(lp), 16, 0, 0)

static __device__ __forceinline__ f16x8 pack8f(const float* p) {
    f16x2 a = __builtin_bit_cast(f16x2, __builtin_amdgcn_cvt_pkrtz(p[0], p[1]));
    f16x2 b = __builtin_bit_cast(f16x2, __builtin_amdgcn_cvt_pkrtz(p[2], p[3]));
    f16x2 c = __builtin_bit_cast(f16x2, __builtin_amdgcn_cvt_pkrtz(p[4], p[5]));
    f16x2 d = __builtin_bit_cast(f16x2, __builtin_amdgcn_cvt_pkrtz(p[6], p[7]));
    f16x8 r;
    r[0] = a[0]; r[1] = a[1]; r[2] = b[0]; r[3] = b[1];
    r[4] = c[0]; r[5] = c[1]; r[6] = d[0]; r[7] = d[1];
    return r;
}

// ---- prep: fp32->fp16 convert of x1,x2 (blocks 0..8191) + transpose-convert of the
// ---- 4 weights into (N,K) f16 (blocks 8192..12287), one launch ----
__global__ __launch_bounds__(256) void prep_kernel(
        const float* __restrict__ x1, const float* __restrict__ x2,
        const float* __restrict__ W0, const float* __restrict__ W1,
        const float* __restrict__ W2, const float* __restrict__ W3,
        _Float16* __restrict__ y1, _Float16* __restrict__ y2,
        _Float16* __restrict__ T0, _Float16* __restrict__ T1,
        _Float16* __restrict__ T2, _Float16* __restrict__ T3) {
    int bx = blockIdx.x, tid = threadIdx.x;
    if (bx < 8192) {
        int i = bx * 256 + tid;              // 2M float4 total
        const float* x = (i < 1048576) ? x1 : x2;
        _Float16* y = (i < 1048576) ? y1 : y2;
        int j = i & 1048575;
        float4 v = ((const float4*)x)[j];
        f16x4 h = { (_Float16)v.x, (_Float16)v.y, (_Float16)v.z, (_Float16)v.w };
        ((f16x4*)y)[j] = h;
    } else {
        int z = (bx - 8192) >> 10;
        const float* W = (z == 0) ? W0 : (z == 1) ? W1 : (z == 2) ? W2 : W3;
        _Float16* WT = (z == 0) ? T0 : (z == 1) ? T1 : (z == 2) ? T2 : T3;
        int t = (bx - 8192) & 1023;
        int c0 = (t & 31) * 32, r0 = (t >> 5) * 32;
        __shared__ float tile[32][33];
        int tx = tid & 31, ty = tid >> 5;    // 32 x 8
#pragma unroll
        for (int i = 0; i < 32; i += 8)
            tile[ty + i][tx] = W[(r0 + ty + i) * 1024 + (c0 + tx)];
        __syncthreads();
#pragma unroll
        for (int i = 0; i < 32; i += 8)
            WT[(c0 + ty + i) * 1024 + (r0 + tx)] = (_Float16)tile[tx][ty + i];
    }
}

// ------------- m97-style MTx128 GEMM body (pre-offset pointers, K=1024) -------------
// block 256 (4 waves, 2x2 over MT x 128), BK=64, global_load_lds w16, 16x16x32 MFMA.
template <int MT, bool OUTF32>
static __device__ __forceinline__ void gemm_body(const _Float16* __restrict__ Atile,
                                                 const _Float16* __restrict__ BTtile,
                                                 void* __restrict__ Ctile,
                                                 _Float16* As, _Float16* Bs) {
    constexpr int AF = MT / 32;              // A staging rounds & m-frags per wave
    const int tid = threadIdx.x, lane = tid & 63, wave = tid >> 6;
    const int wm = wave >> 1, wn = wave & 1;
    const int col = lane & 15, quad = lane >> 4;

    f32x4 acc[AF][4];
#pragma unroll
    for (int i = 0; i < AF; i++)
#pragma unroll
        for (int j = 0; j < 4; j++) acc[i][j] = (f32x4){0.f, 0.f, 0.f, 0.f};

    const int srow = wave * 8 + (lane >> 3);
    const int sch = (lane & 7) * 8;
    const _Float16* Ag = Atile + (size_t)srow * 1024 + sch;
    const _Float16* Bg = BTtile + (size_t)srow * 1024 + sch;
    _Float16* Asl = As + wave * 512;
    _Float16* Bsl = Bs + wave * 512;

    for (int kt = 0; kt < 16; kt++) {
        __syncthreads();
#pragma unroll
        for (int c = 0; c < AF; c++)
            GLOAD_LDS16(Ag + (size_t)(c * 32) * 1024 + kt * 64, Asl + c * 2048);
#pragma unroll
        for (int c = 0; c < 4; c++)
            GLOAD_LDS16(Bg + (size_t)(c * 32) * 1024 + kt * 64, Bsl + c * 2048);
        __syncthreads();
#pragma unroll
        for (int ki = 0; ki < 2; ki++) {
            f16x8 af[AF], bf[4];
#pragma unroll
            for (int i = 0; i < AF; i++)
                af[i] = *(const f16x8*)(As + (wm * (MT / 2) + i * 16 + col) * 64 + ki * 32 + quad * 8);
#pragma unroll
            for (int j = 0; j < 4; j++)
                bf[j] = *(const f16x8*)(Bs + (wn * 64 + j * 16 + col) * 64 + ki * 32 + quad * 8);
#pragma unroll
            for (int i = 0; i < AF; i++)
#pragma unroll
                for (int j = 0; j < 4; j++)
                    acc[i][j] = __builtin_amdgcn_mfma_f32_16x16x32_f16(af[i], bf[j], acc[i][j], 0, 0, 0);
        }
    }

#pragma unroll
    for (int i = 0; i < AF; i++)
#pragma unroll
        for (int ii = 0; ii < 4; ii++) {
            int row = wm * (MT / 2) + i * 16 + quad * 4 + ii;
#pragma unroll
            for (int j = 0; j < 4; j++) {
                int cc = wn * 64 + j * 16 + col;
                if (OUTF32) ((float*)Ctile)[(size_t)row * 1024 + cc] = acc[i][j][ii];
                else ((_Float16*)Ctile)[(size_t)row * 1024 + cc] = (_Float16)acc[i][j][ii];
            }
        }
}

// Fused Q + (KV as N=2048) projections, flat 768-block grid (128x128 tiles):
__global__ __launch_bounds__(256, 3) void gemm_qkv_kernel(
        const _Float16* __restrict__ x1h, const _Float16* __restrict__ x2h,
        const _Float16* __restrict__ WqT, const _Float16* __restrict__ WkvT,
        _Float16* __restrict__ Qh, _Float16* __restrict__ Kh, _Float16* __restrict__ Vh) {
    __shared__ _Float16 As[128 * 64], Bs[128 * 64];
    int gx = blockIdx.x;
    const _Float16 *A, *BT;
    _Float16* C;
    int m0, n0;
    if (gx < 256) {
        m0 = (gx >> 3) * 128; n0 = (gx & 7) * 128;
        A = x1h; BT = WqT + (size_t)n0 * 1024; C = Qh + n0;
    } else {
        int idx = gx - 256;
        m0 = (idx >> 4) * 128;
        int nb = idx & 15;
        n0 = nb * 128;                        // 0..2047 within stacked KV
        A = x2h; BT = WkvT + (size_t)n0 * 1024;
        C = (nb < 8) ? (Kh + n0) : (Vh + (n0 - 1024));
    }
    gemm_body<128, false>(A + (size_t)m0 * 1024, BT, (void*)(C + (size_t)m0 * 1024), As, Bs);
}

// Wo GEMM: 64x128 tiles -> 512 blocks (2 blocks/CU co-residency).
__global__ __launch_bounds__(256, 4) void gemm_wo_kernel(const _Float16* __restrict__ Ah,
                                                         const _Float16* __restrict__ WoT,
                                                         float* __restrict__ out) {
    __shared__ _Float16 As[64 * 64], Bs[128 * 64];
    int gx = blockIdx.x;
    int m0 = (gx >> 3) * 64, n0 = (gx & 7) * 128;
    gemm_body<64, true>(Ah + (size_t)m0 * 1024, WoT + (size_t)n0 * 1024,
                        (void*)(out + (size_t)m0 * 1024 + n0), As, Bs);
}

// ------------- MFMA flash attention (fixed-max softmax), per (b,g) pair -------------
// grid (8 q-chunks, 256 pairs) = 2048 blocks, block 256 (4 waves), 8.2 KB LDS
// (128-key K/V chunks). Empirical co-residency model (R6-R10): blocks/CU ~ 64KB/LDS
// -> ~7 blocks/CU = ~28 waves/CU, 2x R9's residency. VGPR stays ~32 (1 chain).
// Wave: 32 queries x 1024 keys, 32 keys/iter:
//   S32 = Khat.Q^T via ONE mfma_32x32x16; Khat row m = physical key perm(m)
//   (swap bits 2<->3 of low5), so C-layout regs 0-7 / 8-15, exp'd + packed, ARE the
//   B-frags of two mfma_32x32x16 PV calls. PV A rows 0-15 = V^T, rows 16-31 =
//   broadcast ones -> L fused into acc regs 8-15.
// V staged as key-PAIRS (f16x2 b32 writes): halves DS-write instruction count.
__global__ __launch_bounds__(256, 8) void attn_kernel(const _Float16* __restrict__ Qh,
                                                      const _Float16* __restrict__ Kh,
                                                      const _Float16* __restrict__ Vh,
                                                      _Float16* __restrict__ Ah) {
    int pair = blockIdx.y;
    int b = pair >> 6, g = pair & 63;
    __shared__ _Float16 KA[2048];    // [t:4][lane:64][8 halves] pre-permuted A-frags, 4 KB
    __shared__ _Float16 VA[2048];    // [pvblk:8][slot:32][8 halves], slot=head+16*ksel, 4 KB
    __shared__ _Float16 ones[8];

    const _Float16* Kg = Kh + (size_t)(b * 1024) * 1024 + g * 16;
    const _Float16* Vg = Vh + (size_t)(b * 1024) * 1024 + g * 16;
    int tid = threadIdx.x;
    if (tid < 8) ones[tid] = (_Float16)1.f;

    int lane = tid & 63, wave = tid >> 6;    // wave 0..3
    int n = lane & 31, h5 = lane >> 5;       // n = q (S/PV col), also PV A-row m
    int q0 = blockIdx.x * 128 + wave * 32;

    // Q B-frag: B[k=head=h5*8+j][n=q]; fold 0.25*log2(e) -> scores in log2 domain.
    f16x8 qf;
    {
        f16x8 t = *(const f16x8*)(Qh + (size_t)(b * 1024 + q0 + n) * 1024 + g * 16 + h5 * 8);
#pragma unroll
        for (int j = 0; j < 8; j++) qf[j] = (_Float16)((float)t[j] * 0.360673760f);
    }

    f32x16 acc = {0.f, 0.f, 0.f, 0.f, 0.f, 0.f, 0.f, 0.f,
                  0.f, 0.f, 0.f, 0.f, 0.f, 0.f, 0.f, 0.f};
    const f32x16 zero16 = acc;
    // V A-frag source: real V rows for m<16, broadcast ones for m>=16.
    const _Float16* vbase = (n < 16) ? (VA + (n + 16 * h5) * 8) : ones;
    const int vstep = (n < 16) ? 256 : 0;    // advance per pvblk only for real rows

    // staging indices (uniform per thread across chunks)
    const int krow = tid >> 1, kpart = tid & 1;                       // K: 1 task/thread
    const int kpm = (krow & 19) | ((krow & 4) << 1) | ((krow & 8) >> 1);
    const int kdst = (((krow >> 5) * 64) + kpm + 32 * kpart) * 8;
    const int vk0 = (tid >> 1) * 2 & 127, vpart = tid & 1;            // V: threads 0..127
    const int vbase_w = (vk0 >> 4) * 256 + ((vk0 >> 3) & 1) * 128 + vpart * 64 + (vk0 & 7);

    for (int c = 0; c < 8; c++) {            // 128-key chunks
        if (c) __syncthreads();
        // K: permuted staging, one uint4 per thread
        *(uint4*)(KA + kdst) =
            *(const uint4*)(Kg + (size_t)(c * 128 + krow) * 1024 + kpart * 8);
        // V: key-pair transpose, threads 0..127, f16x2 writes
        if (tid < 128) {
            f16x8 v0 = *(const f16x8*)(Vg + (size_t)(c * 128 + vk0) * 1024 + vpart * 8);
            f16x8 v1 = *(const f16x8*)(Vg + (size_t)(c * 128 + vk0 + 1) * 1024 + vpart * 8);
#pragma unroll
            for (int j = 0; j < 8; j++) {
                f16x2 pr; pr[0] = v0[j]; pr[1] = v1[j];
                *(f16x2*)(VA + vbase_w + j * 8) = pr;
            }
        }
        __syncthreads();

#pragma unroll
        for (int t = 0; t < 4; t++) {        // 32 keys per iteration
            f16x8 ak = *(const f16x8*)(KA + (t * 64 + lane) * 8);
            f32x16 s = __builtin_amdgcn_mfma_f32_32x32x16_f16(ak, qf, zero16, 0, 0, 0);
            float p[16];
#pragma unroll
            for (int i = 0; i < 16; i++) p[i] = __builtin_amdgcn_exp2f(s[i]);
            f16x8 pb0 = pack8f(p);           // keys t*32 + 0..15  (k=h5*8+j)
            f16x8 pb1 = pack8f(p + 8);       // keys t*32 + 16..31
            f16x8 av0 = *(const f16x8*)(vbase + (2 * t) * vstep);
            f16x8 av1 = *(const f16x8*)(vbase + (2 * t + 1) * vstep);
            acc = __builtin_amdgcn_mfma_f32_32x32x16_f16(av0, pb0, acc, 0, 0, 0);
            acc = __builtin_amdgcn_mfma_f32_32x32x16_f16(av1, pb1, acc, 0, 0, 0);
        }
    }

    // acc C-layout: col q=n; regs 0-7 -> heads, regs 8-15 -> L (all equal = key-sum).
    float rl = 1.0f / acc[8];
    f16x4 o0, o1;
#pragma unroll
    for (int i = 0; i < 4; i++) o0[i] = (_Float16)(acc[i] * rl);       // heads 4*h5+0..3
#pragma unroll
    for (int i = 0; i < 4; i++) o1[i] = (_Float16)(acc[4 + i] * rl);   // heads 4*h5+8..11
    _Float16* ob = Ah + (size_t)(b * 1024 + q0 + n) * 1024 + g * 16 + h5 * 4;
    *(f16x4*)(ob) = o0;
    *(f16x4*)(ob + 8) = o1;
}

extern "C" void kernel_launch(void* const* d_in, const int* in_sizes, int n_in,
                              void* d_out, int out_size, void* d_ws, size_t ws_size,
                              hipStream_t stream) {
    const float* x1 = (const float*)d_in[0];
    const float* x2 = (const float*)d_in[1];
    const float* Wq = (const float*)d_in[2];
    const float* Wk = (const float*)d_in[3];
    const float* Wv = (const float*)d_in[4];
    const float* Wo = (const float*)d_in[5];

    char* ws = (char*)d_ws;
    const size_t MB = 1u << 20;
    if (ws_size < 56 * MB) return;

    _Float16* x1h = (_Float16*)(ws + 0 * MB);   // 4096x1024
    _Float16* x2h = (_Float16*)(ws + 8 * MB);   // 4096x1024
    _Float16* WqT = (_Float16*)(ws + 16 * MB);  // 1024x1024 (N,K)
    _Float16* WkT = (_Float16*)(ws + 18 * MB);  // contiguous with WvT -> stacked (2048,1024)
    _Float16* WvT = (_Float16*)(ws + 20 * MB);
    _Float16* WoT = (_Float16*)(ws + 22 * MB);
    _Float16* Qh  = (_Float16*)(ws + 24 * MB);  // 4096x1024
    _Float16* Kh  = (_Float16*)(ws + 32 * MB);
    _Float16* Vh  = (_Float16*)(ws + 40 * MB);
    _Float16* Ah  = (_Float16*)(ws + 48 * MB);

    prep_kernel<<<12288, 256, 0, stream>>>(x1, x2, Wq, Wk, Wv, Wo,
                                           x1h, x2h, WqT, WkT, WvT, WoT);

    gemm_qkv_kernel<<<768, 256, 0, stream>>>(x1h, x2h, WqT, WkT, Qh, Kh, Vh);

    attn_kernel<<<dim3(8, 256), 256, 0, stream>>>(Qh, Kh, Vh, Ah);

    gemm_wo_kernel<<<512, 256, 0, stream>>>(Ah, WoT, (float*)d_out);
}